// Round 4
// baseline (922.083 us; speedup 1.0000x reference)
//
#include <hip/hip_runtime.h>
#include <cstdint>
#include <cstddef>

typedef unsigned short u16;
typedef unsigned int u32;

typedef __bf16 bf16x8 __attribute__((ext_vector_type(8)));
typedef float f32x4 __attribute__((ext_vector_type(4)));
typedef u16 u16x8 __attribute__((ext_vector_type(8)));

__device__ __forceinline__ u16 f2bf(float f) {
  union { float f; u32 u; } v; v.f = f;
  u32 r = v.u + 0x7fffu + ((v.u >> 16) & 1u);   // RNE
  return (u16)(r >> 16);
}
__device__ __forceinline__ float bf2f(u16 h) {
  union { u32 u; float f; } v; v.u = ((u32)h) << 16;
  return v.f;
}

// Barriers WITHOUT the vmcnt(0) drain __syncthreads would impose.
// bar_lgkm: drain own LDS writes, then barrier (writer->reader handoff).
// bar_only: plain barrier (reader->writer handoff; reads already retired
// via compiler dep-waits before their MFMA uses).
__device__ __forceinline__ void bar_lgkm() {
  asm volatile("s_waitcnt lgkmcnt(0)\n\ts_barrier" ::: "memory");
}
__device__ __forceinline__ void bar_only() {
  asm volatile("s_barrier" ::: "memory");
}

// ---------------------------------------------------------------------------
// GEMM: C(M,N) = A(M,K)bf16 * Bt(N,K)bf16^T + bias, 128x128 tiles, BK=32.
// Register-staged pipeline: global->VGPR loads issued one FULL iteration
// before their ds_write use, so the compiler's fine-grained vmcnt(N) wait is
// already satisfied. One raw (lgkm-only) barrier per K-step, double LDS buf:
//   W(buf p) -> prefetch(p, k+64) -> bar -> C(buf p)   [p alternates]
// Safety: a wave writing buf p has passed the barrier that followed every
// wave's previous compute on buf p.
// LDS chunk swizzle: chunk(r,c) at slot r*4 + (c ^ ((r>>1)&3)) -> conflict-free.
// ---------------------------------------------------------------------------
template<bool OUT_F32>
__global__ __launch_bounds__(256)
void gemm_bt(const u16* __restrict__ A, const u16* __restrict__ Bt,
             const float* __restrict__ bias, void* __restrict__ C,
             int M, int N, int K) {
  __shared__ __attribute__((aligned(16))) u16 As[2][128*32];
  __shared__ __attribute__((aligned(16))) u16 Bs[2][128*32];
  const int tid  = threadIdx.x;
  const int lane = tid & 63;
  const int wave = tid >> 6;
  const int wm = wave >> 1, wn = wave & 1;
  const int bn = blockIdx.x * 128;
  const int bm = blockIdx.y * 128;
  const int kq = lane >> 4, ml = lane & 15;

  // staging: thread owns chunks (r0,c0),(r0,c0+1); 512 chunks / 256 threads
  const int ci0 = tid * 2;
  const int r0  = ci0 >> 2, c0 = ci0 & 3;
  const u16* agA = A  + (size_t)(bm + r0)*K + c0*8;
  const u16* agB = Bt + (size_t)(bn + r0)*K + c0*8;
  const int sw  = (r0 >> 1) & 3;
  const int s0  = (r0*4 + (c0 ^ sw))*8;          // u16 offsets in LDS
  const int s1  = (r0*4 + ((c0+1) ^ sw))*8;

  uint4 a00, a01, b00, b01;    // set 0 (even K-steps)
  uint4 a10, a11, b10, b11;    // set 1 (odd K-steps)
  a00 = *(const uint4*)(agA + 0);  a01 = *(const uint4*)(agA + 8);
  b00 = *(const uint4*)(agB + 0);  b01 = *(const uint4*)(agB + 8);
  a10 = *(const uint4*)(agA + 32); a11 = *(const uint4*)(agA + 40);
  b10 = *(const uint4*)(agB + 32); b11 = *(const uint4*)(agB + 40);

  f32x4 acc[4][4] = {};

  auto compute = [&](int p) {
    bf16x8 af[4], bfr[4];
#pragma unroll
    for (int t = 0; t < 4; ++t) {
      int ra = wm*64 + t*16 + ml;
      af[t]  = *(const bf16x8*)(&As[p][0] + (size_t)(ra*4 + (kq ^ ((ra >> 1) & 3)))*8);
      int rb = wn*64 + t*16 + ml;
      bfr[t] = *(const bf16x8*)(&Bs[p][0] + (size_t)(rb*4 + (kq ^ ((rb >> 1) & 3)))*8);
    }
#pragma unroll
    for (int i = 0; i < 4; ++i)
#pragma unroll
      for (int j = 0; j < 4; ++j)
        acc[i][j] = __builtin_amdgcn_mfma_f32_16x16x32_bf16(af[i], bfr[j], acc[i][j], 0, 0, 0);
  };

  for (int k0 = 0; k0 < K; k0 += 64) {
    // ---- K-step A (buffer 0): write set0, prefetch set0 for k0+64
    *(uint4*)(&As[0][s0]) = a00;  *(uint4*)(&As[0][s1]) = a01;
    *(uint4*)(&Bs[0][s0]) = b00;  *(uint4*)(&Bs[0][s1]) = b01;
    if (k0 + 64 < K) {
      a00 = *(const uint4*)(agA + k0 + 64); a01 = *(const uint4*)(agA + k0 + 72);
      b00 = *(const uint4*)(agB + k0 + 64); b01 = *(const uint4*)(agB + k0 + 72);
    }
    bar_lgkm();
    compute(0);
    // ---- K-step B (buffer 1): write set1, prefetch set1 for k0+96
    *(uint4*)(&As[1][s0]) = a10;  *(uint4*)(&As[1][s1]) = a11;
    *(uint4*)(&Bs[1][s0]) = b10;  *(uint4*)(&Bs[1][s1]) = b11;
    if (k0 + 96 < K) {
      a10 = *(const uint4*)(agA + k0 + 96);  a11 = *(const uint4*)(agA + k0 + 104);
      b10 = *(const uint4*)(agB + k0 + 96);  b11 = *(const uint4*)(agB + k0 + 104);
    }
    bar_lgkm();
    compute(1);
  }

  // C/D layout: col = lane&15, row = (lane>>4)*4 + reg   [m89/m91 verified]
#pragma unroll
  for (int i = 0; i < 4; ++i) {
    int rg0 = bm + wm*64 + i*16 + kq*4;
#pragma unroll
    for (int j = 0; j < 4; ++j) {
      int cg = bn + wn*64 + j*16 + ml;
      float bv = bias[cg];
#pragma unroll
      for (int r = 0; r < 4; ++r) {
        float v = acc[i][j][r] + bv;
        if (OUT_F32) ((float*)C)[(size_t)(rg0 + r)*N + cg] = v;
        else         ((u16*)C)[(size_t)(rg0 + r)*N + cg]   = f2bf(v);
      }
    }
  }
}

// ---------------------------------------------------------------------------
// Flash attention: grid (qt=16, b*32+head=128), block 256 (4 waves x 16 rows).
// Q fragments live in registers (wave-private rows). K/V staged via the same
// register pipeline: loads for kt+1 issued during compute of kt. Raw barriers
// only (no vmcnt drain). Ps is wave-private -> NO barrier around it.
// Q pre-scaled by (1/sqrt(d))*log2(e); softmax via exp2. Descending qt order.
// ---------------------------------------------------------------------------
__global__ __launch_bounds__(256)
void attn(const u16* __restrict__ Q, const u16* __restrict__ K,
          const u16* __restrict__ V, u16* __restrict__ ctx) {
  __shared__ __attribute__((aligned(16))) u16 Ks[64*128];
  __shared__ __attribute__((aligned(16))) u16 Vs[128*64];
  __shared__ __attribute__((aligned(16))) u16 Ps[4][16*72];  // pad 8: conflict-free
  const int qt  = (int)gridDim.x - 1 - (int)blockIdx.x;
  const int bh  = blockIdx.y;
  const int b   = bh >> 5;
  const int kvh = bh & 3;
  const int tid = threadIdx.x;
  const int lane = tid & 63;
  const int wave = tid >> 6;
  const int kq = lane >> 4, ml = lane & 15;

  const u16* Kg = K + ((size_t)(b*4 + kvh))*1024*128;
  const u16* Vg = V + ((size_t)(b*4 + kvh))*128*1024;

  // Q fragments (A-layout: lane ml = row, k = kq*8+j) straight from global
  const u16* Qrow = Q + ((size_t)bh*1024 + qt*64 + wave*16 + ml)*128;
  bf16x8 aq[4];
#pragma unroll
  for (int ks = 0; ks < 4; ++ks)
    aq[ks] = *(const bf16x8*)(Qrow + ks*32 + kq*8);

  // K/V staging: thread owns 4 chunks of each tile (64 B contiguous global)
  const int kr0 = tid >> 2, kc0 = (tid & 3)*4;        // K: row, chunk base
  const int vd0 = tid >> 1, vc0 = (tid & 1)*4;        // V: d-row, chunk base
  const u16* kgp = Kg + (size_t)kr0*128 + kc0*8;
  const u16* vgp = Vg + (size_t)vd0*1024 + vc0*8;
  uint4 krg[4], vrg[4];
#pragma unroll
  for (int i = 0; i < 4; ++i) {
    krg[i] = *(const uint4*)(kgp + i*8);
    vrg[i] = *(const uint4*)(vgp + i*8);
  }

  f32x4 o[8] = {};
  float m_i[4] = {-1e30f, -1e30f, -1e30f, -1e30f};
  float l_i[4] = {0.f, 0.f, 0.f, 0.f};

  for (int kt = 0; kt <= qt; ++kt) {
    bar_only();                                // all waves done reading kt-1 tiles
#pragma unroll
    for (int i = 0; i < 4; ++i) {              // K: slot = r*16 + (c ^ (r&7))
      *(uint4*)(&Ks[(size_t)(kr0*16 + ((kc0+i) ^ (kr0 & 7)))*8]) = krg[i];
      *(uint4*)(&Vs[(size_t)(vd0*8  + ((vc0+i) ^ (vd0 & 7)))*8]) = vrg[i];
    }
    if (kt < qt) {
#pragma unroll
      for (int i = 0; i < 4; ++i) {
        krg[i] = *(const uint4*)(kgp + (size_t)(kt+1)*64*128 + i*8);
        vrg[i] = *(const uint4*)(vgp + (size_t)(kt+1)*64 + i*8);
      }
    }
    bar_lgkm();                                // K/V tile visible

    // S = Q * K^T  (16 rows x 64 cols per wave)
    f32x4 sf[4] = {};
#pragma unroll
    for (int ks = 0; ks < 4; ++ks) {
      int cq = ks*4 + kq;
#pragma unroll
      for (int nt = 0; nt < 4; ++nt) {
        int rk = nt*16 + ml;
        bf16x8 bk = *(const bf16x8*)(Ks + (size_t)(rk*16 + (cq ^ (rk & 7)))*8);
        sf[nt] = __builtin_amdgcn_mfma_f32_16x16x32_bf16(aq[ks], bk, sf[nt], 0, 0, 0);
      }
    }

    const int i0 = qt*64 + wave*16 + kq*4;     // global q row of reg 0
    if (kt == qt) {                            // causal mask on diagonal tile
#pragma unroll
      for (int nt = 0; nt < 4; ++nt) {
        int jg = kt*64 + nt*16 + ml;
#pragma unroll
        for (int r = 0; r < 4; ++r)
          if (jg > i0 + r) sf[nt][r] = -1e30f;
      }
    }
    float rmax[4] = {-1e30f, -1e30f, -1e30f, -1e30f};
#pragma unroll
    for (int nt = 0; nt < 4; ++nt)
#pragma unroll
      for (int r = 0; r < 4; ++r)
        rmax[r] = fmaxf(rmax[r], sf[nt][r]);
#pragma unroll
    for (int r = 0; r < 4; ++r) {              // row-reduce across the 16 col-lanes
      float v = rmax[r];
      v = fmaxf(v, __shfl_xor(v, 1));
      v = fmaxf(v, __shfl_xor(v, 2));
      v = fmaxf(v, __shfl_xor(v, 4));
      v = fmaxf(v, __shfl_xor(v, 8));
      float mo = m_i[r];
      float mn = fmaxf(mo, v);
      m_i[r] = mn;
      rmax[r] = exp2f(mo - mn);                // alpha
    }
    float rsum[4] = {0.f, 0.f, 0.f, 0.f};
#pragma unroll
    for (int nt = 0; nt < 4; ++nt)
#pragma unroll
      for (int r = 0; r < 4; ++r) {
        float p = exp2f(sf[nt][r] - m_i[r]);
        rsum[r] += p;
        Ps[wave][(kq*4 + r)*72 + nt*16 + ml] = f2bf(p);
      }
#pragma unroll
    for (int r = 0; r < 4; ++r) {
      float v = rsum[r];
      v += __shfl_xor(v, 1);
      v += __shfl_xor(v, 2);
      v += __shfl_xor(v, 4);
      v += __shfl_xor(v, 8);
      l_i[r] = l_i[r]*rmax[r] + v;
    }
#pragma unroll
    for (int dt = 0; dt < 8; ++dt)
#pragma unroll
      for (int r = 0; r < 4; ++r)
        o[dt][r] *= rmax[r];

    // O += P(16x64) * V(64x128).  Ps is wave-private: compiler's own lgkm
    // dep-waits order the write->read; no barrier needed.
#pragma unroll
    for (int ks = 0; ks < 2; ++ks) {
      bf16x8 ap = *(const bf16x8*)(&Ps[wave][ml*72 + ks*32 + kq*8]);
#pragma unroll
      for (int dt = 0; dt < 8; ++dt) {
        int dv = dt*16 + ml;
        int cv = ks*4 + kq;
        bf16x8 bv = *(const bf16x8*)(Vs + (size_t)(dv*8 + (cv ^ (dv & 7)))*8);
        o[dt] = __builtin_amdgcn_mfma_f32_16x16x32_bf16(ap, bv, o[dt], 0, 0, 0);
      }
    }
  }

  const int head = bh & 31;
  float inv[4];
#pragma unroll
  for (int r = 0; r < 4; ++r) inv[r] = 1.f / l_i[r];
  size_t row0 = (size_t)b*1024 + qt*64 + wave*16 + kq*4;
#pragma unroll
  for (int dt = 0; dt < 8; ++dt) {
    int cg = head*128 + dt*16 + ml;
#pragma unroll
    for (int r = 0; r < 4; ++r)
      ctx[(row0 + r)*4096 + cg] = f2bf(o[dt][r]*inv[r]);
  }
}

// ---------------------------------------------------------------------------
// prep kernels
// ---------------------------------------------------------------------------
__global__ void castx(const float* __restrict__ x, u16* __restrict__ xb) {
  size_t i = ((size_t)blockIdx.x*256 + threadIdx.x)*4;
  float4 v = *(const float4*)(x + i);
  ushort4 o; o.x = f2bf(v.x); o.y = f2bf(v.y); o.z = f2bf(v.z); o.w = f2bf(v.w);
  *(ushort4*)(xb + i) = o;
}

// W (K,N) f32 -> Wt (N,K) bf16, 64x64 tiles, 256 threads.
__global__ void wtrans(const float* __restrict__ W, u16* __restrict__ Wt, int K, int N) {
  __shared__ u16 t[64*71 + 8];
  const int n0 = blockIdx.x*64, k0 = blockIdx.y*64;
  const int tid = threadIdx.x;
  const int kr = tid >> 4, nc = (tid & 15)*4;
#pragma unroll
  for (int i = 0; i < 4; ++i) {
    float4 v = *(const float4*)(W + (size_t)(k0 + kr + i*16)*N + n0 + nc);
    u16* d = &t[(kr + i*16)*71 + nc];
    d[0] = f2bf(v.x); d[1] = f2bf(v.y); d[2] = f2bf(v.z); d[3] = f2bf(v.w);
  }
  __syncthreads();
  const int n = tid >> 2, k16 = (tid & 3)*16;
  u16x8 lo, hi;
#pragma unroll
  for (int j = 0; j < 8; ++j) lo[j] = t[(k16 + j)*71 + n];
#pragma unroll
  for (int j = 0; j < 8; ++j) hi[j] = t[(k16 + 8 + j)*71 + n];
  u16* dst = Wt + (size_t)(n0 + n)*K + k0 + k16;
  *(u16x8*)(dst)     = lo;
  *(u16x8*)(dst + 8) = hi;
}

__global__ void packbias(const float* __restrict__ bq, const float* __restrict__ bk,
                         const float* __restrict__ bv, float* __restrict__ out) {
  int i = blockIdx.x*256 + threadIdx.x;
  float v;
  if (i < 4096)      v = bq[i];
  else if (i < 4608) v = bk[i - 4096];
  else               v = bv[i - 4608];
  out[i] = v;
}

// q cols of qkv_lin (ld 5120) -> (b, head, n, d) with RoPE, scaled by (1/sqrt(d))*log2e
__global__ void rope_q(const u16* __restrict__ qkv, u16* __restrict__ qr) {
  int idx = blockIdx.x*256 + threadIdx.x;   // 8388608 pairs
  int dp = idx & 63;
  int head = (idx >> 6) & 31;
  int n = (idx >> 11) & 1023;
  int b = idx >> 21;
  const u16* src = qkv + ((size_t)(b*1024 + n))*5120 + head*128 + dp*2;
  float e = bf2f(src[0]), od = bf2f(src[1]);
  float freq = exp2f((float)dp * -0.2076205059f);   // 10000^(-2dp/128)
  float ang = (float)n * freq;
  float s, c;
  __sincosf(ang, &s, &c);
  const float QS = 0.12751747f;                     // (1/sqrt(128)) * log2(e)
  u16* dst = qr + (((size_t)(b*32 + head))*1024 + n)*128 + dp*2;
  dst[0] = f2bf((e*c - od*s)*QS);
  dst[1] = f2bf((od*c + e*s)*QS);
}

__global__ void rope_k(const u16* __restrict__ qkv, u16* __restrict__ kr) {
  int idx = blockIdx.x*256 + threadIdx.x;   // 1048576 pairs
  int dp = idx & 63;
  int kvh = (idx >> 6) & 3;
  int n = (idx >> 8) & 1023;
  int b = idx >> 18;
  const u16* src = qkv + ((size_t)(b*1024 + n))*5120 + 4096 + kvh*128 + dp*2;
  float e = bf2f(src[0]), od = bf2f(src[1]);
  float freq = exp2f((float)dp * -0.2076205059f);
  float ang = (float)n * freq;
  float s, c;
  __sincosf(ang, &s, &c);
  u16* dst = kr + (((size_t)(b*4 + kvh))*1024 + n)*128 + dp*2;
  dst[0] = f2bf(e*c - od*s);
  dst[1] = f2bf(od*c + e*s);
}

// v cols of qkv_lin -> V^T (b, kvh, d=128, n=1024)
__global__ void vtrans(const u16* __restrict__ qkv, u16* __restrict__ vt) {
  __shared__ u16 t[32][40];
  const int nt = blockIdx.x, dt = blockIdx.y, bk = blockIdx.z;
  const int b = bk >> 2, kvh = bk & 3;
  const int tid = threadIdx.x;
  const int r = tid >> 3, c4 = (tid & 7)*4;
  const u16* src = qkv + ((size_t)(b*1024 + nt*32 + r))*5120 + 4608 + kvh*128 + dt*32 + c4;
#pragma unroll
  for (int i = 0; i < 4; ++i) t[r][c4 + i] = src[i];
  __syncthreads();
  u16* dst = vt + ((size_t)((b*4 + kvh)*128 + dt*32 + r))*1024 + nt*32 + c4;
#pragma unroll
  for (int i = 0; i < 4; ++i) dst[i] = t[c4 + i][r];
}

// ---------------------------------------------------------------------------
extern "C" void kernel_launch(void* const* d_in, const int* in_sizes, int n_in,
                              void* d_out, int out_size, void* d_ws, size_t ws_size,
                              hipStream_t stream) {
  const float* x  = (const float*)d_in[0];
  const float* Wq = (const float*)d_in[1];
  const float* bq = (const float*)d_in[2];
  const float* Wk = (const float*)d_in[3];
  const float* bk = (const float*)d_in[4];
  const float* Wv = (const float*)d_in[5];
  const float* bv = (const float*)d_in[6];
  const float* Wo = (const float*)d_in[7];
  const float* bo = (const float*)d_in[8];
  float* out = (float*)d_out;

  char* ws = (char*)d_ws;
  u16*   xb   = (u16*)(ws + 0);              // 33.5 MB  (x bf16)
  u16*   wqkv = (u16*)(ws + 33554432);       // 41.9 MB  (Wq^T|Wk^T|Wv^T bf16, 5120x4096)
  u16*   wo_t = (u16*)(ws + 75497472);       // 33.5 MB  (Wo^T bf16)
  float* bqkv = (float*)(ws + 109051904);    // 20 KB    (bq|bk|bv)
  u16*   qkvl = (u16*)(ws + 109072384);      // 41.9 MB  (qkv_lin bf16, 4096x5120)
  // dead-buffer reuse after QKV GEMM:
  u16*   qr   = (u16*)(ws + 33554432);       // over wqkv   (b,h,n,d)
  u16*   kr   = (u16*)(ws + 67108864);       //             (b,kvh,n,d)
  u16*   vt   = (u16*)(ws + 71303168);       //             (b,kvh,d,n)
  u16*   ctx  = (u16*)(ws + 0);              // over xb     (b*n, 4096)

  castx<<<16384, 256, 0, stream>>>(x, xb);
  wtrans<<<dim3(64,64), 256, 0, stream>>>(Wq, wqkv, 4096, 4096);
  wtrans<<<dim3(8,64),  256, 0, stream>>>(Wk, wqkv + (size_t)4096*4096, 4096, 512);
  wtrans<<<dim3(8,64),  256, 0, stream>>>(Wv, wqkv + (size_t)4608*4096, 4096, 512);
  wtrans<<<dim3(64,64), 256, 0, stream>>>(Wo, wo_t, 4096, 4096);
  packbias<<<20, 256, 0, stream>>>(bq, bk, bv, bqkv);

  gemm_bt<false><<<dim3(40,32), 256, 0, stream>>>(xb, wqkv, bqkv, qkvl, 4096, 5120, 4096);

  rope_q<<<32768, 256, 0, stream>>>(qkvl, qr);
  rope_k<<<4096,  256, 0, stream>>>(qkvl, kr);
  vtrans<<<dim3(32,4,16), 256, 0, stream>>>(qkvl, vt);

  attn<<<dim3(16,128), 256, 0, stream>>>(qr, kr, vt, ctx);

  gemm_bt<true><<<dim3(32,32), 256, 0, stream>>>(ctx, wo_t, bo, out, 4096, 4096, 4096);
}